// Round 17
// baseline (126.355 us; speedup 1.0000x reference)
//
#include <hip/hip_runtime.h>
#include <stdint.h>

// ---------- helpers ----------
typedef short bf16x8 __attribute__((ext_vector_type(8)));
typedef float f32x4  __attribute__((ext_vector_type(4)));
typedef float f32x2  __attribute__((ext_vector_type(2)));

#define BCAP 2032   // bucket region capacity (slots); mean ~1024, max ~1150

__device__ __forceinline__ uint16_t fbu(float f){
    union { float f; uint32_t i; } v; v.f = f;
    uint32_t r = v.i + 0x7FFFu + ((v.i >> 16) & 1u);
    return (uint16_t)(r >> 16);
}
__device__ __forceinline__ float bfu(uint16_t u){
    union { uint32_t i; float f; } v; v.i = ((uint32_t)u) << 16; return v.f;
}
// pack bf16(v1)<<16 | bf16(v0) by truncation, single v_perm_b32
__device__ __forceinline__ uint32_t pk2(float v0, float v1){
    return __builtin_amdgcn_perm(__float_as_uint(v1), __float_as_uint(v0), 0x07060302u);
}
__device__ __forceinline__ float fexp2(float x){
#if __has_builtin(__builtin_amdgcn_exp2f)
    return __builtin_amdgcn_exp2f(x);
#else
    float r; asm("v_exp_f32 %0, %1" : "=v"(r) : "v"(x)); return r;
#endif
}

// ---------- fused pre-pass: bin (edge sort by bucket) + x cast + weight transpose ----------
// bin payload .x = src | (dst<<16), .y = packed bf16 attr
// w1g fragment-group: j = e + lr*8 + kc*128 + c16*2048  -> w1[(kc*8+e)*256 + c16*16 + lr]
// w2g fragment-group: j = e + lr*8 + kc*128 + c16*4096  -> w2[(kc*8+e)*128 + c16*16 + lr]
__global__ __launch_bounds__(1024) void k_pre(
    const int* __restrict__ src, const int* __restrict__ dst,
    const float* __restrict__ eattr,
    int* __restrict__ gcnt, uint2* __restrict__ breg, int E, int nbkt, int nb_bin,
    const float* __restrict__ x, uint16_t* __restrict__ xb, int n4, int nb_x,
    const float* __restrict__ w1, const float* __restrict__ w2,
    uint16_t* __restrict__ w1g, uint16_t* __restrict__ w2g)
{
    __shared__ uint2 spay[8192];
    __shared__ int cnt[1024];
    __shared__ int base[1024];
    __shared__ int gbase[1024];
    __shared__ int wsum[16];
    int b = blockIdx.x, tid = threadIdx.x;

    if (b >= nb_bin){
        int bb = b - nb_bin;
        if (bb < nb_x){
            int i = bb*1024 + tid;
            if (i < n4){
                float4 v = *(const float4*)(x + (size_t)i*4);
                ushort4 o;
                o.x = fbu(v.x); o.y = fbu(v.y); o.z = fbu(v.z); o.w = fbu(v.w);
                *(ushort4*)(xb + (size_t)i*4) = o;
            }
        } else {
            int j = (bb - nb_x)*1024 + tid;       // [0, 65536)
            if (j < 32768){
                int e = j & 7, lr = (j >> 3) & 15, kc = (j >> 7) & 15, c16 = (j >> 11) & 15;
                w1g[j] = fbu(w1[(size_t)(kc*8 + e)*256 + c16*16 + lr]);
            } else {
                int j2 = j - 32768;
                int e = j2 & 7, lr = (j2 >> 3) & 15, kc = (j2 >> 7) & 31, c16 = (j2 >> 12) & 7;
                w2g[j2] = fbu(w2[(size_t)(kc*8 + e)*128 + c16*16 + lr]);
            }
        }
        return;
    }

    // ---- bin body (register-staged dst, verified r14) ----
    int lane = tid & 63, w = tid >> 6;
    int e0 = b * 8192;
    int nE = E - e0; if (nE > 8192) nE = 8192;

    for (int i = tid; i < 1024; i += 1024) cnt[i] = 0;
    __syncthreads();
    int d[8];
    #pragma unroll
    for (int j = 0; j < 8; ++j){
        int i = tid + j*1024;
        d[j] = (i < nE) ? dst[e0 + i] : -1;
        if (i < nE) atomicAdd(&cnt[d[j] >> 6], 1);
    }
    __syncthreads();
    int v = cnt[tid];
    int sv = v;
    #pragma unroll
    for (int o = 1; o < 64; o <<= 1){ int t2 = __shfl_up(sv, o); if (lane >= o) sv += t2; }
    if (lane == 63) wsum[w] = sv;
    __syncthreads();
    if (tid < 16){
        int ws_ = wsum[tid];
        #pragma unroll
        for (int o = 1; o < 16; o <<= 1){ int t2 = __shfl_up(ws_, o); if (tid >= o) ws_ += t2; }
        wsum[tid] = ws_;
    }
    __syncthreads();
    int excl = (sv - v) + ((w == 0) ? 0 : wsum[w-1]);
    base[tid] = excl;
    if (tid < nbkt && v > 0) gbase[tid] = atomicAdd(&gcnt[tid], v);
    cnt[tid] = excl;
    __syncthreads();
    #pragma unroll
    for (int j = 0; j < 8; ++j){
        int i = tid + j*1024;
        if (i < nE){
            int e = e0 + i;
            int s = src[e];
            float2 a = *(const float2*)(eattr + (size_t)e*2);
            int bkt = d[j] >> 6;
            int pos = atomicAdd(&cnt[bkt], 1);
            uint2 p;
            p.x = (uint32_t)s | ((uint32_t)d[j] << 16);
            p.y = (uint32_t)fbu(a.x) | ((uint32_t)fbu(a.y) << 16);
            spay[pos] = p;
        }
    }
    __syncthreads();
    for (int i = tid; i < nE; i += 1024){
        uint2 p = spay[i];
        int bkt = (int)(p.x >> 22);
        int g = gbase[bkt] + (i - base[bkt]);
        breg[(size_t)bkt * BCAP + g] = p;
    }
}

// ---------- exclusive scan of bucket totals ----------
__global__ __launch_bounds__(1024) void k_bscan(const int* __restrict__ gcnt,
                                                int* __restrict__ bbase, int nbkt){
    __shared__ int wsum[16];
    int tid = threadIdx.x;
    int lane = tid & 63, w = tid >> 6;
    int v = (tid < nbkt) ? gcnt[tid] : 0;
    int sv = v;
    #pragma unroll
    for (int o = 1; o < 64; o <<= 1){ int t2 = __shfl_up(sv, o); if (lane >= o) sv += t2; }
    if (lane == 63) wsum[w] = sv;
    __syncthreads();
    if (tid < 16){
        int ws_ = wsum[tid];
        #pragma unroll
        for (int o = 1; o < 16; o <<= 1){ int t2 = __shfl_up(ws_, o); if (tid >= o) ws_ += t2; }
        wsum[tid] = ws_;
    }
    __syncthreads();
    if (tid < nbkt) bbase[tid] = (sv - v) + ((w == 0) ? 0 : wsum[w-1]);
}

// ---------- phase B: per-bucket node sort in LDS, coalesced se write + offs ----------
__global__ __launch_bounds__(256) void k_bsort(
    const uint2* __restrict__ breg, const int* __restrict__ gcnt,
    const int* __restrict__ bbase, uint2* __restrict__ se,
    int* __restrict__ offs, int Nn)
{
    __shared__ uint2 pay[BCAP];
    __shared__ uint2 pay2[BCAP];
    __shared__ int ncnt[64];
    int b = blockIdx.x;
    int tid = threadIdx.x;
    int cnt = gcnt[b];
    int base = bbase[b];
    if (b == 0 && tid == 0) offs[0] = 0;
    if (tid < 64) ncnt[tid] = 0;
    __syncthreads();
    for (int i = tid; i < cnt; i += 256){
        uint2 p = breg[(size_t)b * BCAP + i];
        pay[i] = p;
        atomicAdd(&ncnt[(p.x >> 16) & 63], 1);
    }
    __syncthreads();
    if (tid < 64){
        int v = ncnt[tid];
        int sv = v;
        #pragma unroll
        for (int o = 1; o < 64; o <<= 1){ int t2 = __shfl_up(sv, o); if (tid >= o) sv += t2; }
        int node = b*64 + tid;
        if (node < Nn) offs[node + 1] = base + sv;
        ncnt[tid] = sv - v;   // running index = exclusive base
    }
    __syncthreads();
    for (int i = tid; i < cnt; i += 256){
        uint2 p = pay[i];
        int pos = atomicAdd(&ncnt[(p.x >> 16) & 63], 1);
        pay2[pos] = make_uint2(p.x & 0xFFFFu, p.y);
    }
    __syncthreads();
    for (int i = tid; i < cnt; i += 256)
        se[base + i] = pay2[i];
}

// ---------- per-node softmax aggregation: one wave/node, 32-edge predicated batches ----------
__global__ __launch_bounds__(256) void k_agg(
    const uint16_t* __restrict__ xb, const uint2* __restrict__ se,
    const float* __restrict__ ew, const float* __restrict__ ebias,
    const float* __restrict__ tptr, const int* __restrict__ offs,
    uint16_t* __restrict__ h, int Nn)
{
    int lane = threadIdx.x & 63;
    int n = blockIdx.x * 4 + (threadIdx.x >> 6);
    if (n >= Nn) return;
    int d0 = lane * 2;
    float tt2 = tptr[0] * 1.44269504f;        // t * log2(e), folded into weights
    f32x2 wa0 = { ew[d0]*tt2,     ew[d0+1]*tt2 };
    f32x2 wa1 = { ew[128+d0]*tt2, ew[128+d0+1]*tt2 };
    f32x2 bbt = { ebias[d0]*tt2,  ebias[d0+1]*tt2 };
    const f32x2 zero2 = { 0.f, 0.f };
    int beg = offs[n], end = offs[n+1];
    f32x2 den = zero2, num = zero2;
    // 32-edge batches; deg~Poisson(16) so ~95% of nodes need exactly ONE chain
    for (int i0 = beg; i0 < end; i0 += 32){
        int cnt = end - i0; if (cnt > 32) cnt = 32;
        uint2 md = make_uint2(0u, 0u);
        if ((lane & 31) < cnt) md = se[i0 + (lane & 31)];
        int mxs = (int)md.x;
        int mys = (int)md.y;
        uint32_t xw[32];
        #pragma unroll
        for (int j = 0; j < 32; ++j){
            uint32_t sj = (uint32_t)__builtin_amdgcn_readlane(mxs, j) & 0xFFFFu;
            if (j < cnt) xw[j] = *(const uint32_t*)(xb + ((size_t)sj << 7) + d0);
        }
        #pragma unroll
        for (int j = 0; j < 32; ++j){
            if (j < cnt){
                uint32_t aw = (uint32_t)__builtin_amdgcn_readlane(mys, j);
                float a0 = bfu((uint16_t)aw), a1 = bfu((uint16_t)(aw >> 16));
                uint32_t u = xw[j];
                f32x2 xv = { bfu((uint16_t)u), bfu((uint16_t)(u >> 16)) };
                f32x2 p = xv * tt2 + (wa0 * a0 + wa1 * a1 + bbt);
                p = __builtin_elementwise_max(p, zero2);
                f32x2 ex = { fexp2(p.x), fexp2(p.y) };
                den += ex;
                num += ex * p;
            }
        }
    }
    // epilogue: agg = (num / tt2) / den + eps  (num is in scaled domain)
    float agg0 = num.x / fmaxf(den.x * tt2, 1e-16f) + 1e-7f;
    float agg1 = num.y / fmaxf(den.y * tt2, 1e-16f) + 1e-7f;
    uint32_t xr = *(const uint32_t*)(xb + (size_t)n*128 + d0);
    float v0 = agg0 + bfu((uint16_t)xr);
    float v1 = agg1 + bfu((uint16_t)(xr >> 16));
    *(uint32_t*)(h + (size_t)n*128 + d0) = pk2(v0, v1);
}

// ---------- GEMM1: h[N,128] @ w1 + b1 -> h1 bf16 (fragment-group layout) ----------
// h1g layout: element (r,k) -> h1g[((r>>4)*32 + (k>>3))*128 + (r&15)*8 + (k&7)]
__global__ __launch_bounds__(256) void k_gemm1(
    const uint16_t* __restrict__ h, const uint16_t* __restrict__ w1g,
    const float* __restrict__ b1, float* __restrict__ bnsum, float* __restrict__ bnss,
    uint16_t* __restrict__ h1, int M)
{
    __shared__ uint16_t tile[64*264];
    int lane = threadIdx.x & 63;
    int wid  = threadIdx.x >> 6;
    int row0 = blockIdx.x * 64;
    int cb   = wid * 64;
    int lr   = lane & 15;
    int lkg  = lane >> 4;
    int lk   = lkg * 8;
    f32x4 acc[4][4] = {};
    #pragma unroll
    for (int ks = 0; ks < 4; ++ks){
        int k = ks*32 + lk;
        bf16x8 a[4], b[4];
        #pragma unroll
        for (int rt = 0; rt < 4; ++rt){
            int r = row0 + rt*16 + lr; if (r > M-1) r = M-1;
            a[rt] = *(const bf16x8*)(h + (size_t)r*128 + k);
        }
        #pragma unroll
        for (int ct = 0; ct < 4; ++ct){
            int c16 = wid*4 + ct;
            b[ct] = *(const bf16x8*)(w1g + ((size_t)(c16*16 + ks*4 + lkg) << 7) + lr*8);
        }
        #pragma unroll
        for (int rt = 0; rt < 4; ++rt)
            #pragma unroll
            for (int ct = 0; ct < 4; ++ct)
                acc[rt][ct] = __builtin_amdgcn_mfma_f32_16x16x32_bf16(a[rt], b[ct], acc[rt][ct], 0, 0, 0);
    }
    int co = lkg * 4;
    #pragma unroll
    for (int ct = 0; ct < 4; ++ct){
        int c = cb + ct*16 + lr;
        float bias = b1[c];
        float ps = 0.f, ps2 = 0.f;
        #pragma unroll
        for (int rt = 0; rt < 4; ++rt){
            #pragma unroll
            for (int rg = 0; rg < 4; ++rg){
                int rl = rt*16 + co + rg;
                float v = acc[rt][ct][rg] + bias;
                tile[rl*264 + c] = fbu(v);
                if (row0 + rl < M){ ps += v; ps2 += v*v; }
            }
        }
        ps  += __shfl_xor(ps, 16);  ps  += __shfl_xor(ps, 32);
        ps2 += __shfl_xor(ps2, 16); ps2 += __shfl_xor(ps2, 32);
        if (lkg == 0){
            atomicAdd(&bnsum[c], ps);
            atomicAdd(&bnss[c], ps2);
        }
    }
    __syncthreads();
    // coalesced store in fragment-group layout:
    // idx8 = rt16l*512 + kc*16 + rr ; dest = h1g + row0*256 + idx8*8 (16B/thread)
    #pragma unroll
    for (int j = 0; j < 8; ++j){
        int idx8  = j*256 + threadIdx.x;
        int rr    = idx8 & 15;
        int kc    = (idx8 >> 4) & 31;
        int rt16l = idx8 >> 9;
        if (row0 + rt16l*16 + rr < M){
            bf16x8 v = *(const bf16x8*)(tile + (rt16l*16 + rr)*264 + kc*8);
            *(bf16x8*)(h1 + (size_t)row0*256 + (size_t)idx8*8) = v;
        }
    }
}

// ---------- GEMM2: relu(bn(h1g)) @ w2 + b2, fused BN-finalize + LayerNorm + ELU ----------
// A and B loads both contiguous 1KB per wave (fragment-group h1g / w2g)
__global__ __launch_bounds__(256) void k_gemm2(
    const uint16_t* __restrict__ h1, const uint16_t* __restrict__ w2g,
    const float* __restrict__ bnsum, const float* __restrict__ bnss,
    const float* __restrict__ bng, const float* __restrict__ bnb,
    const float* __restrict__ b2, const float* __restrict__ lng,
    const float* __restrict__ lnb, float* __restrict__ out, int M, float invM)
{
    __shared__ float sbn_s[256], tbn_s[256];
    __shared__ float2 red[64][2];    // per-row (sum, sum2) per col-half
    int tid = threadIdx.x;
    {
        float mu  = bnsum[tid] * invM;
        float var = bnss[tid] * invM - mu*mu;
        float rstd = rsqrtf(fmaxf(var, 0.f) + 1e-5f);
        float sc = rstd * bng[tid];
        sbn_s[tid] = sc;
        tbn_s[tid] = bnb[tid] - mu * sc;
    }
    __syncthreads();
    int lane = tid & 63;
    int wid  = tid >> 6;
    int wm = wid >> 1, wn = wid & 1;
    int row0 = blockIdx.x * 64;
    int lr = lane & 15, lkg = lane >> 4;
    int rt16max = (M - 1) >> 4;
    f32x4 acc[2][4] = {};
    #pragma unroll
    for (int ks = 0; ks < 8; ++ks){
        int k = ks*32 + lkg*8;
        float s[8], t[8];
        *(float4*)&s[0] = *(const float4*)(sbn_s + k);
        *(float4*)&s[4] = *(const float4*)(sbn_s + k + 4);
        *(float4*)&t[0] = *(const float4*)(tbn_s + k);
        *(float4*)&t[4] = *(const float4*)(tbn_s + k + 4);
        bf16x8 a[2], b[4];
        #pragma unroll
        for (int rt = 0; rt < 2; ++rt){
            int rt16 = (row0 >> 4) + wm*2 + rt;
            if (rt16 > rt16max) rt16 = rt16max;
            bf16x8 hv = *(const bf16x8*)(h1 + (size_t)rt16*4096 + (size_t)(ks*4 + lkg)*128 + lr*8);
            union { uint32_t u[4]; bf16x8 v; } pk;
            #pragma unroll
            for (int jj = 0; jj < 4; ++jj){
                float v0 = fmaf(bfu((uint16_t)hv[2*jj]),   s[2*jj],   t[2*jj]);
                float v1 = fmaf(bfu((uint16_t)hv[2*jj+1]), s[2*jj+1], t[2*jj+1]);
                v0 = fmaxf(v0, 0.f); v1 = fmaxf(v1, 0.f);
                pk.u[jj] = pk2(v0, v1);
            }
            a[rt] = pk.v;
        }
        #pragma unroll
        for (int ct = 0; ct < 4; ++ct){
            int c16 = wn*4 + ct;
            b[ct] = *(const bf16x8*)(w2g + ((size_t)(c16*32 + ks*4 + lkg) << 7) + lr*8);
        }
        #pragma unroll
        for (int rt = 0; rt < 2; ++rt)
            #pragma unroll
            for (int ct = 0; ct < 4; ++ct)
                acc[rt][ct] = __builtin_amdgcn_mfma_f32_16x16x32_bf16(a[rt], b[ct], acc[rt][ct], 0, 0, 0);
    }
    // bias into acc; preload LN params per ct
    float lngv[4], lnbv[4];
    #pragma unroll
    for (int ct = 0; ct < 4; ++ct){
        int cl = wn*64 + ct*16 + lr;
        float bias = b2[cl];
        lngv[ct] = lng[cl];
        lnbv[ct] = lnb[cl];
        #pragma unroll
        for (int rt = 0; rt < 2; ++rt)
            #pragma unroll
            for (int rg = 0; rg < 4; ++rg)
                acc[rt][ct][rg] += bias;
    }
    // per-row partials: reduce Σv, Σv² over the 16-lane lr-group
    #pragma unroll
    for (int rt = 0; rt < 2; ++rt){
        #pragma unroll
        for (int rg = 0; rg < 4; ++rg){
            float s = 0.f, s2 = 0.f;
            #pragma unroll
            for (int ct = 0; ct < 4; ++ct){
                float v = acc[rt][ct][rg];
                s += v; s2 = fmaf(v, v, s2);
            }
            s  += __shfl_xor(s, 1);  s  += __shfl_xor(s, 2);  s  += __shfl_xor(s, 4);  s  += __shfl_xor(s, 8);
            s2 += __shfl_xor(s2, 1); s2 += __shfl_xor(s2, 2); s2 += __shfl_xor(s2, 4); s2 += __shfl_xor(s2, 8);
            if (lr == 0){
                int rl = wm*32 + rt*16 + lkg*4 + rg;
                red[rl][wn] = make_float2(s, s2);
            }
        }
    }
    __syncthreads();
    // normalize in registers, store fp32 directly
    #pragma unroll
    for (int rt = 0; rt < 2; ++rt){
        #pragma unroll
        for (int rg = 0; rg < 4; ++rg){
            int rl = wm*32 + rt*16 + lkg*4 + rg;
            int gr = row0 + rl;
            float2 p0 = red[rl][0], p1 = red[rl][1];
            float sum  = p0.x + p1.x;
            float sum2 = p0.y + p1.y;
            float mu = sum * (1.f/128.f);
            float var = sum2 * (1.f/128.f) - mu*mu;
            float rstd = rsqrtf(fmaxf(var, 0.f) + 1e-5f);
            if (gr < M){
                #pragma unroll
                for (int ct = 0; ct < 4; ++ct){
                    int cl = wn*64 + ct*16 + lr;
                    float v = (acc[rt][ct][rg] - mu) * rstd * lngv[ct] + lnbv[ct];
                    v = (v > 0.f) ? v : (fexp2(v * 1.44269504f) - 1.f);
                    out[(size_t)gr*128 + cl] = v;
                }
            }
        }
    }
}

// ---------- launcher ----------
extern "C" void kernel_launch(void* const* d_in, const int* in_sizes, int n_in,
                              void* d_out, int out_size, void* d_ws, size_t ws_size,
                              hipStream_t stream)
{
    (void)n_in; (void)out_size; (void)ws_size;
    const float* x     = (const float*)d_in[0];
    const float* eattr = (const float*)d_in[1];
    const float* ew    = (const float*)d_in[2];
    const float* eb    = (const float*)d_in[3];
    const float* t     = (const float*)d_in[4];
    const float* w1    = (const float*)d_in[5];
    const float* b1    = (const float*)d_in[6];
    const float* bng   = (const float*)d_in[7];
    const float* bnb   = (const float*)d_in[8];
    const float* w2    = (const float*)d_in[9];
    const float* b2    = (const float*)d_in[10];
    const float* lng   = (const float*)d_in[11];
    const float* lnb   = (const float*)d_in[12];
    const int*   eidx  = (const int*)d_in[13];
    int Nn = in_sizes[0] / 128;
    int E  = in_sizes[13] / 2;
    int nbkt = (Nn + 63) >> 6;          // 782

    char* ws = (char*)d_ws;
    size_t off = 0;
    auto alloc = [&](size_t bytes)->char*{
        char* p = ws + off;
        off += (bytes + 511) & ~(size_t)511;
        return p;
    };
    char* zstart   = ws;
    int*   gcnt    = (int*)  alloc((size_t)nbkt * 4);
    float* bnsum   = (float*)alloc(256 * 4);
    float* bnss    = (float*)alloc(256 * 4);
    size_t zlen    = off;
    int*   bbase   = (int*)  alloc((size_t)nbkt * 4);
    int*   offs    = (int*)  alloc((size_t)(Nn + 1) * 4);
    uint2* se      = (uint2*)alloc((size_t)E * 8);
    uint16_t* w1g  = (uint16_t*)alloc(128 * 256 * 2);
    uint16_t* w2g  = (uint16_t*)alloc(128 * 256 * 2);
    uint16_t* hbuf = (uint16_t*)alloc((size_t)Nn * 128 * 2);   // bf16 h = agg + x

    // d_out overlays:
    //   xb   = d_out[0 : Nn*128*2)              (bf16 x; live until k_agg)
    //   breg = d_out[Nn*128*2 : +nbkt*BCAP*8)   (bucket regions; live k_pre..k_bsort)
    //   h1g  = all of d_out                     (gemm1 output, fragment-group layout;
    //                                            then gemm2 final fp32)
    uint16_t* xb   = (uint16_t*)d_out;
    uint2*    breg = (uint2*)((char*)d_out + (size_t)Nn * 128 * 2);
    uint16_t* h1   = (uint16_t*)d_out;
    float*    fo   = (float*)d_out;

    int n4     = Nn * 32;
    int nb_bin = (E + 8191) / 8192;         // 98
    int nb_x   = (n4 + 1023) / 1024;        // 1563
    int nb_w   = (2*128*256 + 1023) / 1024; // 64

    hipMemsetAsync(zstart, 0, zlen, stream);
    k_pre<<<nb_bin + nb_x + nb_w, 1024, 0, stream>>>(
        eidx, eidx + E, eattr, gcnt, breg, E, nbkt, nb_bin,
        x, xb, n4, nb_x, w1, w2, w1g, w2g);
    k_bscan<<<1, 1024, 0, stream>>>(gcnt, bbase, nbkt);
    k_bsort<<<nbkt, 256, 0, stream>>>(breg, gcnt, bbase, se, offs, Nn);
    k_agg<<<(Nn + 3) / 4, 256, 0, stream>>>(xb, se, ew, eb, t, offs, hbuf, Nn);
    k_gemm1<<<(Nn + 63) / 64, 256, 0, stream>>>(hbuf, w1g, b1, bnsum, bnss, h1, Nn);
    k_gemm2<<<(Nn + 63) / 64, 256, 0, stream>>>(h1, w2g, bnsum, bnss, bng, bnb, b2, lng, lnb, fo, Nn, 1.0f/(float)Nn);
}

// Round 18
// 122.063 us; speedup vs baseline: 1.0352x; 1.0352x over previous
//
#include <hip/hip_runtime.h>
#include <stdint.h>

// ---------- helpers ----------
typedef short bf16x8 __attribute__((ext_vector_type(8)));
typedef float f32x4  __attribute__((ext_vector_type(4)));
typedef float f32x2  __attribute__((ext_vector_type(2)));

#define BCAP 2032   // bucket region capacity (slots); mean ~1024, max ~1150

__device__ __forceinline__ uint16_t fbu(float f){
    union { float f; uint32_t i; } v; v.f = f;
    uint32_t r = v.i + 0x7FFFu + ((v.i >> 16) & 1u);
    return (uint16_t)(r >> 16);
}
__device__ __forceinline__ float bfu(uint16_t u){
    union { uint32_t i; float f; } v; v.i = ((uint32_t)u) << 16; return v.f;
}
// pack bf16(v1)<<16 | bf16(v0) by truncation, single v_perm_b32
__device__ __forceinline__ uint32_t pk2(float v0, float v1){
    return __builtin_amdgcn_perm(__float_as_uint(v1), __float_as_uint(v0), 0x07060302u);
}
__device__ __forceinline__ float fexp2(float x){
#if __has_builtin(__builtin_amdgcn_exp2f)
    return __builtin_amdgcn_exp2f(x);
#else
    float r; asm("v_exp_f32 %0, %1" : "=v"(r) : "v"(x)); return r;
#endif
}

// ---------- fused pre-pass: bin (edge sort by bucket) + x cast + weight transpose ----------
// bin payload .x = src | (dst<<16), .y = packed bf16 attr
// w1g fragment-group: j = e + lr*8 + kc*128 + c16*2048  -> w1[(kc*8+e)*256 + c16*16 + lr]
// w2g fragment-group: j = e + lr*8 + kc*128 + c16*4096  -> w2[(kc*8+e)*128 + c16*16 + lr]
__global__ __launch_bounds__(1024) void k_pre(
    const int* __restrict__ src, const int* __restrict__ dst,
    const float* __restrict__ eattr,
    int* __restrict__ gcnt, uint2* __restrict__ breg, int E, int nbkt, int nb_bin,
    const float* __restrict__ x, uint16_t* __restrict__ xb, int n4, int nb_x,
    const float* __restrict__ w1, const float* __restrict__ w2,
    uint16_t* __restrict__ w1g, uint16_t* __restrict__ w2g)
{
    __shared__ uint2 spay[8192];
    __shared__ int cnt[1024];
    __shared__ int base[1024];
    __shared__ int gbase[1024];
    __shared__ int wsum[16];
    int b = blockIdx.x, tid = threadIdx.x;

    if (b >= nb_bin){
        int bb = b - nb_bin;
        if (bb < nb_x){
            int i = bb*1024 + tid;
            if (i < n4){
                float4 v = *(const float4*)(x + (size_t)i*4);
                ushort4 o;
                o.x = fbu(v.x); o.y = fbu(v.y); o.z = fbu(v.z); o.w = fbu(v.w);
                *(ushort4*)(xb + (size_t)i*4) = o;
            }
        } else {
            int j = (bb - nb_x)*1024 + tid;       // [0, 65536)
            if (j < 32768){
                int e = j & 7, lr = (j >> 3) & 15, kc = (j >> 7) & 15, c16 = (j >> 11) & 15;
                w1g[j] = fbu(w1[(size_t)(kc*8 + e)*256 + c16*16 + lr]);
            } else {
                int j2 = j - 32768;
                int e = j2 & 7, lr = (j2 >> 3) & 15, kc = (j2 >> 7) & 31, c16 = (j2 >> 12) & 7;
                w2g[j2] = fbu(w2[(size_t)(kc*8 + e)*128 + c16*16 + lr]);
            }
        }
        return;
    }

    // ---- bin body (register-staged dst, verified r14) ----
    int lane = tid & 63, w = tid >> 6;
    int e0 = b * 8192;
    int nE = E - e0; if (nE > 8192) nE = 8192;

    for (int i = tid; i < 1024; i += 1024) cnt[i] = 0;
    __syncthreads();
    int d[8];
    #pragma unroll
    for (int j = 0; j < 8; ++j){
        int i = tid + j*1024;
        d[j] = (i < nE) ? dst[e0 + i] : -1;
        if (i < nE) atomicAdd(&cnt[d[j] >> 6], 1);
    }
    __syncthreads();
    int v = cnt[tid];
    int sv = v;
    #pragma unroll
    for (int o = 1; o < 64; o <<= 1){ int t2 = __shfl_up(sv, o); if (lane >= o) sv += t2; }
    if (lane == 63) wsum[w] = sv;
    __syncthreads();
    if (tid < 16){
        int ws_ = wsum[tid];
        #pragma unroll
        for (int o = 1; o < 16; o <<= 1){ int t2 = __shfl_up(ws_, o); if (tid >= o) ws_ += t2; }
        wsum[tid] = ws_;
    }
    __syncthreads();
    int excl = (sv - v) + ((w == 0) ? 0 : wsum[w-1]);
    base[tid] = excl;
    if (tid < nbkt && v > 0) gbase[tid] = atomicAdd(&gcnt[tid], v);
    cnt[tid] = excl;
    __syncthreads();
    #pragma unroll
    for (int j = 0; j < 8; ++j){
        int i = tid + j*1024;
        if (i < nE){
            int e = e0 + i;
            int s = src[e];
            float2 a = *(const float2*)(eattr + (size_t)e*2);
            int bkt = d[j] >> 6;
            int pos = atomicAdd(&cnt[bkt], 1);
            uint2 p;
            p.x = (uint32_t)s | ((uint32_t)d[j] << 16);
            p.y = (uint32_t)fbu(a.x) | ((uint32_t)fbu(a.y) << 16);
            spay[pos] = p;
        }
    }
    __syncthreads();
    for (int i = tid; i < nE; i += 1024){
        uint2 p = spay[i];
        int bkt = (int)(p.x >> 22);
        int g = gbase[bkt] + (i - base[bkt]);
        breg[(size_t)bkt * BCAP + g] = p;
    }
}

// ---------- exclusive scan of bucket totals ----------
__global__ __launch_bounds__(1024) void k_bscan(const int* __restrict__ gcnt,
                                                int* __restrict__ bbase, int nbkt){
    __shared__ int wsum[16];
    int tid = threadIdx.x;
    int lane = tid & 63, w = tid >> 6;
    int v = (tid < nbkt) ? gcnt[tid] : 0;
    int sv = v;
    #pragma unroll
    for (int o = 1; o < 64; o <<= 1){ int t2 = __shfl_up(sv, o); if (lane >= o) sv += t2; }
    if (lane == 63) wsum[w] = sv;
    __syncthreads();
    if (tid < 16){
        int ws_ = wsum[tid];
        #pragma unroll
        for (int o = 1; o < 16; o <<= 1){ int t2 = __shfl_up(ws_, o); if (tid >= o) ws_ += t2; }
        wsum[tid] = ws_;
    }
    __syncthreads();
    if (tid < nbkt) bbase[tid] = (sv - v) + ((w == 0) ? 0 : wsum[w-1]);
}

// ---------- phase B: per-bucket node sort in LDS, coalesced se write + offs ----------
__global__ __launch_bounds__(256) void k_bsort(
    const uint2* __restrict__ breg, const int* __restrict__ gcnt,
    const int* __restrict__ bbase, uint2* __restrict__ se,
    int* __restrict__ offs, int Nn)
{
    __shared__ uint2 pay[BCAP];
    __shared__ uint2 pay2[BCAP];
    __shared__ int ncnt[64];
    int b = blockIdx.x;
    int tid = threadIdx.x;
    int cnt = gcnt[b];
    int base = bbase[b];
    if (b == 0 && tid == 0) offs[0] = 0;
    if (tid < 64) ncnt[tid] = 0;
    __syncthreads();
    for (int i = tid; i < cnt; i += 256){
        uint2 p = breg[(size_t)b * BCAP + i];
        pay[i] = p;
        atomicAdd(&ncnt[(p.x >> 16) & 63], 1);
    }
    __syncthreads();
    if (tid < 64){
        int v = ncnt[tid];
        int sv = v;
        #pragma unroll
        for (int o = 1; o < 64; o <<= 1){ int t2 = __shfl_up(sv, o); if (tid >= o) sv += t2; }
        int node = b*64 + tid;
        if (node < Nn) offs[node + 1] = base + sv;
        ncnt[tid] = sv - v;   // running index = exclusive base
    }
    __syncthreads();
    for (int i = tid; i < cnt; i += 256){
        uint2 p = pay[i];
        int pos = atomicAdd(&ncnt[(p.x >> 16) & 63], 1);
        pay2[pos] = make_uint2(p.x & 0xFFFFu, p.y);
    }
    __syncthreads();
    for (int i = tid; i < cnt; i += 256)
        se[base + i] = pay2[i];
}

// ---------- per-node softmax aggregation: one wave/node, packed f32x2 math ----------
__global__ __launch_bounds__(256) void k_agg(
    const uint16_t* __restrict__ xb, const uint2* __restrict__ se,
    const float* __restrict__ ew, const float* __restrict__ ebias,
    const float* __restrict__ tptr, const int* __restrict__ offs,
    uint16_t* __restrict__ h, int Nn)
{
    int lane = threadIdx.x & 63;
    int n = blockIdx.x * 4 + (threadIdx.x >> 6);
    if (n >= Nn) return;
    int d0 = lane * 2;
    float tt2 = tptr[0] * 1.44269504f;        // t * log2(e), folded into weights
    f32x2 wa0 = { ew[d0]*tt2,     ew[d0+1]*tt2 };
    f32x2 wa1 = { ew[128+d0]*tt2, ew[128+d0+1]*tt2 };
    f32x2 bbt = { ebias[d0]*tt2,  ebias[d0+1]*tt2 };
    const f32x2 zero2 = { 0.f, 0.f };
    int beg = offs[n], end = offs[n+1];
    f32x2 den = zero2, num = zero2;
    int i0 = beg;
    // main loop: full 16-edge batches, no predication
    for (; i0 + 16 <= end; i0 += 16){
        uint2 md = se[i0 + (lane & 15)];
        int mxs = (int)md.x;
        int mys = (int)md.y;
        uint32_t xw[16];
        #pragma unroll
        for (int j = 0; j < 16; ++j){
            uint32_t sj = (uint32_t)__builtin_amdgcn_readlane(mxs, j) & 0xFFFFu;
            xw[j] = *(const uint32_t*)(xb + ((size_t)sj << 7) + d0);
        }
        #pragma unroll
        for (int j = 0; j < 16; ++j){
            uint32_t aw = (uint32_t)__builtin_amdgcn_readlane(mys, j);
            float a0 = bfu((uint16_t)aw), a1 = bfu((uint16_t)(aw >> 16));
            uint32_t u = xw[j];
            f32x2 xv = { bfu((uint16_t)u), bfu((uint16_t)(u >> 16)) };
            f32x2 p = xv * tt2 + (wa0 * a0 + wa1 * a1 + bbt);
            p = __builtin_elementwise_max(p, zero2);
            f32x2 ex = { fexp2(p.x), fexp2(p.y) };
            den += ex;
            num += ex * p;
        }
    }
    // tail
    int rem = end - i0;
    if (rem > 0){
        uint2 md = make_uint2(0u, 0u);
        if ((lane & 15) < rem) md = se[i0 + (lane & 15)];
        int mxs = (int)md.x;
        int mys = (int)md.y;
        uint32_t xw[16];
        #pragma unroll
        for (int j = 0; j < 16; ++j){
            uint32_t sj = (uint32_t)__builtin_amdgcn_readlane(mxs, j) & 0xFFFFu;
            if (j < rem) xw[j] = *(const uint32_t*)(xb + ((size_t)sj << 7) + d0);
        }
        #pragma unroll
        for (int j = 0; j < 16; ++j){
            if (j < rem){
                uint32_t aw = (uint32_t)__builtin_amdgcn_readlane(mys, j);
                float a0 = bfu((uint16_t)aw), a1 = bfu((uint16_t)(aw >> 16));
                uint32_t u = xw[j];
                f32x2 xv = { bfu((uint16_t)u), bfu((uint16_t)(u >> 16)) };
                f32x2 p = xv * tt2 + (wa0 * a0 + wa1 * a1 + bbt);
                p = __builtin_elementwise_max(p, zero2);
                f32x2 ex = { fexp2(p.x), fexp2(p.y) };
                den += ex;
                num += ex * p;
            }
        }
    }
    // epilogue: agg = (num / tt2) / den + eps  (num is in scaled domain)
    float agg0 = num.x / fmaxf(den.x * tt2, 1e-16f) + 1e-7f;
    float agg1 = num.y / fmaxf(den.y * tt2, 1e-16f) + 1e-7f;
    uint32_t xr = *(const uint32_t*)(xb + (size_t)n*128 + d0);
    float v0 = agg0 + bfu((uint16_t)xr);
    float v1 = agg1 + bfu((uint16_t)(xr >> 16));
    *(uint32_t*)(h + (size_t)n*128 + d0) = pk2(v0, v1);
}

// ---------- GEMM1: h[N,128] @ w1 + b1 -> h1 bf16 (fragment-group layout) ----------
// h1g layout: element (r,k) -> h1g[((r>>4)*32 + (k>>3))*128 + (r&15)*8 + (k&7)]
__global__ __launch_bounds__(256) void k_gemm1(
    const uint16_t* __restrict__ h, const uint16_t* __restrict__ w1g,
    const float* __restrict__ b1, float* __restrict__ bnsum, float* __restrict__ bnss,
    uint16_t* __restrict__ h1, int M)
{
    __shared__ uint16_t tile[64*264];
    int lane = threadIdx.x & 63;
    int wid  = threadIdx.x >> 6;
    int row0 = blockIdx.x * 64;
    int cb   = wid * 64;
    int lr   = lane & 15;
    int lkg  = lane >> 4;
    int lk   = lkg * 8;
    f32x4 acc[4][4] = {};
    #pragma unroll
    for (int ks = 0; ks < 4; ++ks){
        int k = ks*32 + lk;
        bf16x8 a[4], b[4];
        #pragma unroll
        for (int rt = 0; rt < 4; ++rt){
            int r = row0 + rt*16 + lr; if (r > M-1) r = M-1;
            a[rt] = *(const bf16x8*)(h + (size_t)r*128 + k);
        }
        #pragma unroll
        for (int ct = 0; ct < 4; ++ct){
            int c16 = wid*4 + ct;
            b[ct] = *(const bf16x8*)(w1g + ((size_t)(c16*16 + ks*4 + lkg) << 7) + lr*8);
        }
        #pragma unroll
        for (int rt = 0; rt < 4; ++rt)
            #pragma unroll
            for (int ct = 0; ct < 4; ++ct)
                acc[rt][ct] = __builtin_amdgcn_mfma_f32_16x16x32_bf16(a[rt], b[ct], acc[rt][ct], 0, 0, 0);
    }
    int co = lkg * 4;
    #pragma unroll
    for (int ct = 0; ct < 4; ++ct){
        int c = cb + ct*16 + lr;
        float bias = b1[c];
        float ps = 0.f, ps2 = 0.f;
        #pragma unroll
        for (int rt = 0; rt < 4; ++rt){
            #pragma unroll
            for (int rg = 0; rg < 4; ++rg){
                int rl = rt*16 + co + rg;
                float v = acc[rt][ct][rg] + bias;
                tile[rl*264 + c] = fbu(v);
                if (row0 + rl < M){ ps += v; ps2 += v*v; }
            }
        }
        ps  += __shfl_xor(ps, 16);  ps  += __shfl_xor(ps, 32);
        ps2 += __shfl_xor(ps2, 16); ps2 += __shfl_xor(ps2, 32);
        if (lkg == 0){
            atomicAdd(&bnsum[c], ps);
            atomicAdd(&bnss[c], ps2);
        }
    }
    __syncthreads();
    // coalesced store in fragment-group layout:
    // idx8 = rt16l*512 + kc*16 + rr ; dest = h1g + row0*256 + idx8*8 (16B/thread)
    #pragma unroll
    for (int j = 0; j < 8; ++j){
        int idx8  = j*256 + threadIdx.x;
        int rr    = idx8 & 15;
        int kc    = (idx8 >> 4) & 31;
        int rt16l = idx8 >> 9;
        if (row0 + rt16l*16 + rr < M){
            bf16x8 v = *(const bf16x8*)(tile + (rt16l*16 + rr)*264 + kc*8);
            *(bf16x8*)(h1 + (size_t)row0*256 + (size_t)idx8*8) = v;
        }
    }
}

// ---------- GEMM2: relu(bn(h1g)) @ w2 + b2, fused BN-finalize + LayerNorm + ELU ----------
// A and B loads both contiguous 1KB per wave (fragment-group h1g / w2g)
__global__ __launch_bounds__(256) void k_gemm2(
    const uint16_t* __restrict__ h1, const uint16_t* __restrict__ w2g,
    const float* __restrict__ bnsum, const float* __restrict__ bnss,
    const float* __restrict__ bng, const float* __restrict__ bnb,
    const float* __restrict__ b2, const float* __restrict__ lng,
    const float* __restrict__ lnb, float* __restrict__ out, int M, float invM)
{
    __shared__ float sbn_s[256], tbn_s[256];
    __shared__ float2 red[64][2];    // per-row (sum, sum2) per col-half
    int tid = threadIdx.x;
    {
        float mu  = bnsum[tid] * invM;
        float var = bnss[tid] * invM - mu*mu;
        float rstd = rsqrtf(fmaxf(var, 0.f) + 1e-5f);
        float sc = rstd * bng[tid];
        sbn_s[tid] = sc;
        tbn_s[tid] = bnb[tid] - mu * sc;
    }
    __syncthreads();
    int lane = tid & 63;
    int wid  = tid >> 6;
    int wm = wid >> 1, wn = wid & 1;
    int row0 = blockIdx.x * 64;
    int lr = lane & 15, lkg = lane >> 4;
    int rt16max = (M - 1) >> 4;
    f32x4 acc[2][4] = {};
    #pragma unroll
    for (int ks = 0; ks < 8; ++ks){
        int k = ks*32 + lkg*8;
        float s[8], t[8];
        *(float4*)&s[0] = *(const float4*)(sbn_s + k);
        *(float4*)&s[4] = *(const float4*)(sbn_s + k + 4);
        *(float4*)&t[0] = *(const float4*)(tbn_s + k);
        *(float4*)&t[4] = *(const float4*)(tbn_s + k + 4);
        bf16x8 a[2], b[4];
        #pragma unroll
        for (int rt = 0; rt < 2; ++rt){
            int rt16 = (row0 >> 4) + wm*2 + rt;
            if (rt16 > rt16max) rt16 = rt16max;
            bf16x8 hv = *(const bf16x8*)(h1 + (size_t)rt16*4096 + (size_t)(ks*4 + lkg)*128 + lr*8);
            union { uint32_t u[4]; bf16x8 v; } pk;
            #pragma unroll
            for (int jj = 0; jj < 4; ++jj){
                float v0 = fmaf(bfu((uint16_t)hv[2*jj]),   s[2*jj],   t[2*jj]);
                float v1 = fmaf(bfu((uint16_t)hv[2*jj+1]), s[2*jj+1], t[2*jj+1]);
                v0 = fmaxf(v0, 0.f); v1 = fmaxf(v1, 0.f);
                pk.u[jj] = pk2(v0, v1);
            }
            a[rt] = pk.v;
        }
        #pragma unroll
        for (int ct = 0; ct < 4; ++ct){
            int c16 = wn*4 + ct;
            b[ct] = *(const bf16x8*)(w2g + ((size_t)(c16*32 + ks*4 + lkg) << 7) + lr*8);
        }
        #pragma unroll
        for (int rt = 0; rt < 2; ++rt)
            #pragma unroll
            for (int ct = 0; ct < 4; ++ct)
                acc[rt][ct] = __builtin_amdgcn_mfma_f32_16x16x32_bf16(a[rt], b[ct], acc[rt][ct], 0, 0, 0);
    }
    // bias into acc; preload LN params per ct
    float lngv[4], lnbv[4];
    #pragma unroll
    for (int ct = 0; ct < 4; ++ct){
        int cl = wn*64 + ct*16 + lr;
        float bias = b2[cl];
        lngv[ct] = lng[cl];
        lnbv[ct] = lnb[cl];
        #pragma unroll
        for (int rt = 0; rt < 2; ++rt)
            #pragma unroll
            for (int rg = 0; rg < 4; ++rg)
                acc[rt][ct][rg] += bias;
    }
    // per-row partials: reduce Σv, Σv² over the 16-lane lr-group
    #pragma unroll
    for (int rt = 0; rt < 2; ++rt){
        #pragma unroll
        for (int rg = 0; rg < 4; ++rg){
            float s = 0.f, s2 = 0.f;
            #pragma unroll
            for (int ct = 0; ct < 4; ++ct){
                float v = acc[rt][ct][rg];
                s += v; s2 = fmaf(v, v, s2);
            }
            s  += __shfl_xor(s, 1);  s  += __shfl_xor(s, 2);  s  += __shfl_xor(s, 4);  s  += __shfl_xor(s, 8);
            s2 += __shfl_xor(s2, 1); s2 += __shfl_xor(s2, 2); s2 += __shfl_xor(s2, 4); s2 += __shfl_xor(s2, 8);
            if (lr == 0){
                int rl = wm*32 + rt*16 + lkg*4 + rg;
                red[rl][wn] = make_float2(s, s2);
            }
        }
    }
    __syncthreads();
    // normalize in registers, store fp32 directly
    #pragma unroll
    for (int rt = 0; rt < 2; ++rt){
        #pragma unroll
        for (int rg = 0; rg < 4; ++rg){
            int rl = wm*32 + rt*16 + lkg*4 + rg;
            int gr = row0 + rl;
            float2 p0 = red[rl][0], p1 = red[rl][1];
            float sum  = p0.x + p1.x;
            float sum2 = p0.y + p1.y;
            float mu = sum * (1.f/128.f);
            float var = sum2 * (1.f/128.f) - mu*mu;
            float rstd = rsqrtf(fmaxf(var, 0.f) + 1e-5f);
            if (gr < M){
                #pragma unroll
                for (int ct = 0; ct < 4; ++ct){
                    int cl = wn*64 + ct*16 + lr;
                    float v = (acc[rt][ct][rg] - mu) * rstd * lngv[ct] + lnbv[ct];
                    v = (v > 0.f) ? v : (fexp2(v * 1.44269504f) - 1.f);
                    out[(size_t)gr*128 + cl] = v;
                }
            }
        }
    }
}

// ---------- launcher ----------
extern "C" void kernel_launch(void* const* d_in, const int* in_sizes, int n_in,
                              void* d_out, int out_size, void* d_ws, size_t ws_size,
                              hipStream_t stream)
{
    (void)n_in; (void)out_size; (void)ws_size;
    const float* x     = (const float*)d_in[0];
    const float* eattr = (const float*)d_in[1];
    const float* ew    = (const float*)d_in[2];
    const float* eb    = (const float*)d_in[3];
    const float* t     = (const float*)d_in[4];
    const float* w1    = (const float*)d_in[5];
    const float* b1    = (const float*)d_in[6];
    const float* bng   = (const float*)d_in[7];
    const float* bnb   = (const float*)d_in[8];
    const float* w2    = (const float*)d_in[9];
    const float* b2    = (const float*)d_in[10];
    const float* lng   = (const float*)d_in[11];
    const float* lnb   = (const float*)d_in[12];
    const int*   eidx  = (const int*)d_in[13];
    int Nn = in_sizes[0] / 128;
    int E  = in_sizes[13] / 2;
    int nbkt = (Nn + 63) >> 6;          // 782

    char* ws = (char*)d_ws;
    size_t off = 0;
    auto alloc = [&](size_t bytes)->char*{
        char* p = ws + off;
        off += (bytes + 511) & ~(size_t)511;
        return p;
    };
    char* zstart   = ws;
    int*   gcnt    = (int*)  alloc((size_t)nbkt * 4);
    float* bnsum   = (float*)alloc(256 * 4);
    float* bnss    = (float*)alloc(256 * 4);
    size_t zlen    = off;
    int*   bbase   = (int*)  alloc((size_t)nbkt * 4);
    int*   offs    = (int*)  alloc((size_t)(Nn + 1) * 4);
    uint2* se      = (uint2*)alloc((size_t)E * 8);
    uint16_t* w1g  = (uint16_t*)alloc(128 * 256 * 2);
    uint16_t* w2g  = (uint16_t*)alloc(128 * 256 * 2);
    uint16_t* hbuf = (uint16_t*)alloc((size_t)Nn * 128 * 2);   // bf16 h = agg + x

    // d_out overlays:
    //   xb   = d_out[0 : Nn*128*2)              (bf16 x; live until k_agg)
    //   breg = d_out[Nn*128*2 : +nbkt*BCAP*8)   (bucket regions; live k_pre..k_bsort)
    //   h1g  = all of d_out                     (gemm1 output, fragment-group layout;
    //                                            then gemm2 final fp32)
    uint16_t* xb   = (uint16_t*)d_out;
    uint2*    breg = (uint2*)((char*)d_out + (size_t)Nn * 128 * 2);
    uint16_t* h1   = (uint16_t*)d_out;
    float*    fo   = (float*)d_out;

    int n4     = Nn * 32;
    int nb_bin = (E + 8191) / 8192;         // 98
    int nb_x   = (n4 + 1023) / 1024;        // 1563
    int nb_w   = (2*128*256 + 1023) / 1024; // 64

    hipMemsetAsync(zstart, 0, zlen, stream);
    k_pre<<<nb_bin + nb_x + nb_w, 1024, 0, stream>>>(
        eidx, eidx + E, eattr, gcnt, breg, E, nbkt, nb_bin,
        x, xb, n4, nb_x, w1, w2, w1g, w2g);
    k_bscan<<<1, 1024, 0, stream>>>(gcnt, bbase, nbkt);
    k_bsort<<<nbkt, 256, 0, stream>>>(breg, gcnt, bbase, se, offs, Nn);
    k_agg<<<(Nn + 3) / 4, 256, 0, stream>>>(xb, se, ew, eb, t, offs, hbuf, Nn);
    k_gemm1<<<(Nn + 63) / 64, 256, 0, stream>>>(hbuf, w1g, b1, bnsum, bnss, h1, Nn);
    k_gemm2<<<(Nn + 63) / 64, 256, 0, stream>>>(h1, w2g, bnsum, bnss, bng, bnb, b2, lng, lnb, fo, Nn, 1.0f/(float)Nn);
}

// Round 19
// 121.718 us; speedup vs baseline: 1.0381x; 1.0028x over previous
//
#include <hip/hip_runtime.h>
#include <stdint.h>

// ---------- helpers ----------
typedef short bf16x8 __attribute__((ext_vector_type(8)));
typedef float f32x4  __attribute__((ext_vector_type(4)));
typedef float f32x2  __attribute__((ext_vector_type(2)));

#define BCAP 2032   // bucket region capacity (slots); mean ~1024, max ~1150

__device__ __forceinline__ uint16_t fbu(float f){
    union { float f; uint32_t i; } v; v.f = f;
    uint32_t r = v.i + 0x7FFFu + ((v.i >> 16) & 1u);
    return (uint16_t)(r >> 16);
}
__device__ __forceinline__ float bfu(uint16_t u){
    union { uint32_t i; float f; } v; v.i = ((uint32_t)u) << 16; return v.f;
}
// pack bf16(v1)<<16 | bf16(v0) by truncation, single v_perm_b32
__device__ __forceinline__ uint32_t pk2(float v0, float v1){
    return __builtin_amdgcn_perm(__float_as_uint(v1), __float_as_uint(v0), 0x07060302u);
}
__device__ __forceinline__ float fexp2(float x){
#if __has_builtin(__builtin_amdgcn_exp2f)
    return __builtin_amdgcn_exp2f(x);
#else
    float r; asm("v_exp_f32 %0, %1" : "=v"(r) : "v"(x)); return r;
#endif
}

// ---------- fused pre-pass: bin (edge sort by bucket) + x cast + weight transpose ----------
// bin payload .x = src | (dst<<16), .y = packed bf16 attr
// w1g fragment-group: j = e + lr*8 + kc*128 + c16*2048  -> w1[(kc*8+e)*256 + c16*16 + lr]
// w2g fragment-group: j = e + lr*8 + kc*128 + c16*4096  -> w2[(kc*8+e)*128 + c16*16 + lr]
__global__ __launch_bounds__(1024) void k_pre(
    const int* __restrict__ src, const int* __restrict__ dst,
    const float* __restrict__ eattr,
    int* __restrict__ gcnt, uint2* __restrict__ breg, int E, int nbkt, int nb_bin,
    const float* __restrict__ x, uint16_t* __restrict__ xb, int n4, int nb_x,
    const float* __restrict__ w1, const float* __restrict__ w2,
    uint16_t* __restrict__ w1g, uint16_t* __restrict__ w2g)
{
    __shared__ uint2 spay[8192];
    __shared__ int cnt[1024];
    __shared__ int base[1024];
    __shared__ int gbase[1024];
    __shared__ int wsum[16];
    int b = blockIdx.x, tid = threadIdx.x;

    if (b >= nb_bin){
        int bb = b - nb_bin;
        if (bb < nb_x){
            int i = bb*1024 + tid;
            if (i < n4){
                float4 v = *(const float4*)(x + (size_t)i*4);
                ushort4 o;
                o.x = fbu(v.x); o.y = fbu(v.y); o.z = fbu(v.z); o.w = fbu(v.w);
                *(ushort4*)(xb + (size_t)i*4) = o;
            }
        } else {
            int j = (bb - nb_x)*1024 + tid;       // [0, 65536)
            if (j < 32768){
                int e = j & 7, lr = (j >> 3) & 15, kc = (j >> 7) & 15, c16 = (j >> 11) & 15;
                w1g[j] = fbu(w1[(size_t)(kc*8 + e)*256 + c16*16 + lr]);
            } else {
                int j2 = j - 32768;
                int e = j2 & 7, lr = (j2 >> 3) & 15, kc = (j2 >> 7) & 31, c16 = (j2 >> 12) & 7;
                w2g[j2] = fbu(w2[(size_t)(kc*8 + e)*128 + c16*16 + lr]);
            }
        }
        return;
    }

    // ---- bin body (register-staged dst, verified r14) ----
    int lane = tid & 63, w = tid >> 6;
    int e0 = b * 8192;
    int nE = E - e0; if (nE > 8192) nE = 8192;

    for (int i = tid; i < 1024; i += 1024) cnt[i] = 0;
    __syncthreads();
    int d[8];
    #pragma unroll
    for (int j = 0; j < 8; ++j){
        int i = tid + j*1024;
        d[j] = (i < nE) ? dst[e0 + i] : -1;
        if (i < nE) atomicAdd(&cnt[d[j] >> 6], 1);
    }
    __syncthreads();
    int v = cnt[tid];
    int sv = v;
    #pragma unroll
    for (int o = 1; o < 64; o <<= 1){ int t2 = __shfl_up(sv, o); if (lane >= o) sv += t2; }
    if (lane == 63) wsum[w] = sv;
    __syncthreads();
    if (tid < 16){
        int ws_ = wsum[tid];
        #pragma unroll
        for (int o = 1; o < 16; o <<= 1){ int t2 = __shfl_up(ws_, o); if (tid >= o) ws_ += t2; }
        wsum[tid] = ws_;
    }
    __syncthreads();
    int excl = (sv - v) + ((w == 0) ? 0 : wsum[w-1]);
    base[tid] = excl;
    if (tid < nbkt && v > 0) gbase[tid] = atomicAdd(&gcnt[tid], v);
    cnt[tid] = excl;
    __syncthreads();
    #pragma unroll
    for (int j = 0; j < 8; ++j){
        int i = tid + j*1024;
        if (i < nE){
            int e = e0 + i;
            int s = src[e];
            float2 a = *(const float2*)(eattr + (size_t)e*2);
            int bkt = d[j] >> 6;
            int pos = atomicAdd(&cnt[bkt], 1);
            uint2 p;
            p.x = (uint32_t)s | ((uint32_t)d[j] << 16);
            p.y = (uint32_t)fbu(a.x) | ((uint32_t)fbu(a.y) << 16);
            spay[pos] = p;
        }
    }
    __syncthreads();
    for (int i = tid; i < nE; i += 1024){
        uint2 p = spay[i];
        int bkt = (int)(p.x >> 22);
        int g = gbase[bkt] + (i - base[bkt]);
        breg[(size_t)bkt * BCAP + g] = p;
    }
}

// ---------- exclusive scan of bucket totals ----------
__global__ __launch_bounds__(1024) void k_bscan(const int* __restrict__ gcnt,
                                                int* __restrict__ bbase, int nbkt){
    __shared__ int wsum[16];
    int tid = threadIdx.x;
    int lane = tid & 63, w = tid >> 6;
    int v = (tid < nbkt) ? gcnt[tid] : 0;
    int sv = v;
    #pragma unroll
    for (int o = 1; o < 64; o <<= 1){ int t2 = __shfl_up(sv, o); if (lane >= o) sv += t2; }
    if (lane == 63) wsum[w] = sv;
    __syncthreads();
    if (tid < 16){
        int ws_ = wsum[tid];
        #pragma unroll
        for (int o = 1; o < 16; o <<= 1){ int t2 = __shfl_up(ws_, o); if (tid >= o) ws_ += t2; }
        wsum[tid] = ws_;
    }
    __syncthreads();
    if (tid < nbkt) bbase[tid] = (sv - v) + ((w == 0) ? 0 : wsum[w-1]);
}

// ---------- phase B: per-bucket node sort in LDS, coalesced se write + offs ----------
__global__ __launch_bounds__(256) void k_bsort(
    const uint2* __restrict__ breg, const int* __restrict__ gcnt,
    const int* __restrict__ bbase, uint2* __restrict__ se,
    int* __restrict__ offs, int Nn)
{
    __shared__ uint2 pay[BCAP];
    __shared__ uint2 pay2[BCAP];
    __shared__ int ncnt[64];
    int b = blockIdx.x;
    int tid = threadIdx.x;
    int cnt = gcnt[b];
    int base = bbase[b];
    if (b == 0 && tid == 0) offs[0] = 0;
    if (tid < 64) ncnt[tid] = 0;
    __syncthreads();
    for (int i = tid; i < cnt; i += 256){
        uint2 p = breg[(size_t)b * BCAP + i];
        pay[i] = p;
        atomicAdd(&ncnt[(p.x >> 16) & 63], 1);
    }
    __syncthreads();
    if (tid < 64){
        int v = ncnt[tid];
        int sv = v;
        #pragma unroll
        for (int o = 1; o < 64; o <<= 1){ int t2 = __shfl_up(sv, o); if (tid >= o) sv += t2; }
        int node = b*64 + tid;
        if (node < Nn) offs[node + 1] = base + sv;
        ncnt[tid] = sv - v;   // running index = exclusive base
    }
    __syncthreads();
    for (int i = tid; i < cnt; i += 256){
        uint2 p = pay[i];
        int pos = atomicAdd(&ncnt[(p.x >> 16) & 63], 1);
        pay2[pos] = make_uint2(p.x & 0xFFFFu, p.y);
    }
    __syncthreads();
    for (int i = tid; i < cnt; i += 256)
        se[base + i] = pay2[i];
}

// ---------- per-node softmax aggregation: one wave/node, 2-wave blocks for packing ----------
__global__ __launch_bounds__(128) void k_agg(
    const uint16_t* __restrict__ xb, const uint2* __restrict__ se,
    const float* __restrict__ ew, const float* __restrict__ ebias,
    const float* __restrict__ tptr, const int* __restrict__ offs,
    uint16_t* __restrict__ h, int Nn)
{
    int lane = threadIdx.x & 63;
    int n = blockIdx.x * 2 + (threadIdx.x >> 6);
    if (n >= Nn) return;
    int d0 = lane * 2;
    float tt2 = tptr[0] * 1.44269504f;        // t * log2(e), folded into weights
    f32x2 wa0 = { ew[d0]*tt2,     ew[d0+1]*tt2 };
    f32x2 wa1 = { ew[128+d0]*tt2, ew[128+d0+1]*tt2 };
    f32x2 bbt = { ebias[d0]*tt2,  ebias[d0+1]*tt2 };
    const f32x2 zero2 = { 0.f, 0.f };
    int beg = offs[n], end = offs[n+1];
    f32x2 den = zero2, num = zero2;
    int i0 = beg;
    // main loop: full 16-edge batches, no predication
    for (; i0 + 16 <= end; i0 += 16){
        uint2 md = se[i0 + (lane & 15)];
        int mxs = (int)md.x;
        int mys = (int)md.y;
        uint32_t xw[16];
        #pragma unroll
        for (int j = 0; j < 16; ++j){
            uint32_t sj = (uint32_t)__builtin_amdgcn_readlane(mxs, j) & 0xFFFFu;
            xw[j] = *(const uint32_t*)(xb + ((size_t)sj << 7) + d0);
        }
        #pragma unroll
        for (int j = 0; j < 16; ++j){
            uint32_t aw = (uint32_t)__builtin_amdgcn_readlane(mys, j);
            float a0 = bfu((uint16_t)aw), a1 = bfu((uint16_t)(aw >> 16));
            uint32_t u = xw[j];
            f32x2 xv = { bfu((uint16_t)u), bfu((uint16_t)(u >> 16)) };
            f32x2 p = xv * tt2 + (wa0 * a0 + wa1 * a1 + bbt);
            p = __builtin_elementwise_max(p, zero2);
            f32x2 ex = { fexp2(p.x), fexp2(p.y) };
            den += ex;
            num += ex * p;
        }
    }
    // tail
    int rem = end - i0;
    if (rem > 0){
        uint2 md = make_uint2(0u, 0u);
        if ((lane & 15) < rem) md = se[i0 + (lane & 15)];
        int mxs = (int)md.x;
        int mys = (int)md.y;
        uint32_t xw[16];
        #pragma unroll
        for (int j = 0; j < 16; ++j){
            uint32_t sj = (uint32_t)__builtin_amdgcn_readlane(mxs, j) & 0xFFFFu;
            if (j < rem) xw[j] = *(const uint32_t*)(xb + ((size_t)sj << 7) + d0);
        }
        #pragma unroll
        for (int j = 0; j < 16; ++j){
            if (j < rem){
                uint32_t aw = (uint32_t)__builtin_amdgcn_readlane(mys, j);
                float a0 = bfu((uint16_t)aw), a1 = bfu((uint16_t)(aw >> 16));
                uint32_t u = xw[j];
                f32x2 xv = { bfu((uint16_t)u), bfu((uint16_t)(u >> 16)) };
                f32x2 p = xv * tt2 + (wa0 * a0 + wa1 * a1 + bbt);
                p = __builtin_elementwise_max(p, zero2);
                f32x2 ex = { fexp2(p.x), fexp2(p.y) };
                den += ex;
                num += ex * p;
            }
        }
    }
    // epilogue: agg = (num / tt2) / den + eps  (num is in scaled domain)
    float agg0 = num.x / fmaxf(den.x * tt2, 1e-16f) + 1e-7f;
    float agg1 = num.y / fmaxf(den.y * tt2, 1e-16f) + 1e-7f;
    uint32_t xr = *(const uint32_t*)(xb + (size_t)n*128 + d0);
    float v0 = agg0 + bfu((uint16_t)xr);
    float v1 = agg1 + bfu((uint16_t)(xr >> 16));
    *(uint32_t*)(h + (size_t)n*128 + d0) = pk2(v0, v1);
}

// ---------- GEMM1: h[N,128] @ w1 + b1 -> h1 bf16 (fragment-group layout) ----------
// h1g layout: element (r,k) -> h1g[((r>>4)*32 + (k>>3))*128 + (r&15)*8 + (k&7)]
__global__ __launch_bounds__(256) void k_gemm1(
    const uint16_t* __restrict__ h, const uint16_t* __restrict__ w1g,
    const float* __restrict__ b1, float* __restrict__ bnsum, float* __restrict__ bnss,
    uint16_t* __restrict__ h1, int M)
{
    __shared__ uint16_t tile[64*264];
    int lane = threadIdx.x & 63;
    int wid  = threadIdx.x >> 6;
    int row0 = blockIdx.x * 64;
    int cb   = wid * 64;
    int lr   = lane & 15;
    int lkg  = lane >> 4;
    int lk   = lkg * 8;
    f32x4 acc[4][4] = {};
    #pragma unroll
    for (int ks = 0; ks < 4; ++ks){
        int k = ks*32 + lk;
        bf16x8 a[4], b[4];
        #pragma unroll
        for (int rt = 0; rt < 4; ++rt){
            int r = row0 + rt*16 + lr; if (r > M-1) r = M-1;
            a[rt] = *(const bf16x8*)(h + (size_t)r*128 + k);
        }
        #pragma unroll
        for (int ct = 0; ct < 4; ++ct){
            int c16 = wid*4 + ct;
            b[ct] = *(const bf16x8*)(w1g + ((size_t)(c16*16 + ks*4 + lkg) << 7) + lr*8);
        }
        #pragma unroll
        for (int rt = 0; rt < 4; ++rt)
            #pragma unroll
            for (int ct = 0; ct < 4; ++ct)
                acc[rt][ct] = __builtin_amdgcn_mfma_f32_16x16x32_bf16(a[rt], b[ct], acc[rt][ct], 0, 0, 0);
    }
    int co = lkg * 4;
    #pragma unroll
    for (int ct = 0; ct < 4; ++ct){
        int c = cb + ct*16 + lr;
        float bias = b1[c];
        float ps = 0.f, ps2 = 0.f;
        #pragma unroll
        for (int rt = 0; rt < 4; ++rt){
            #pragma unroll
            for (int rg = 0; rg < 4; ++rg){
                int rl = rt*16 + co + rg;
                float v = acc[rt][ct][rg] + bias;
                tile[rl*264 + c] = fbu(v);
                if (row0 + rl < M){ ps += v; ps2 += v*v; }
            }
        }
        ps  += __shfl_xor(ps, 16);  ps  += __shfl_xor(ps, 32);
        ps2 += __shfl_xor(ps2, 16); ps2 += __shfl_xor(ps2, 32);
        if (lkg == 0){
            atomicAdd(&bnsum[c], ps);
            atomicAdd(&bnss[c], ps2);
        }
    }
    __syncthreads();
    // coalesced store in fragment-group layout:
    // idx8 = rt16l*512 + kc*16 + rr ; dest = h1g + row0*256 + idx8*8 (16B/thread)
    #pragma unroll
    for (int j = 0; j < 8; ++j){
        int idx8  = j*256 + threadIdx.x;
        int rr    = idx8 & 15;
        int kc    = (idx8 >> 4) & 31;
        int rt16l = idx8 >> 9;
        if (row0 + rt16l*16 + rr < M){
            bf16x8 v = *(const bf16x8*)(tile + (rt16l*16 + rr)*264 + kc*8);
            *(bf16x8*)(h1 + (size_t)row0*256 + (size_t)idx8*8) = v;
        }
    }
}

// ---------- GEMM2: relu(bn(h1g)) @ w2 + b2, fused BN-finalize + LayerNorm + ELU ----------
// A and B loads both contiguous 1KB per wave (fragment-group h1g / w2g)
__global__ __launch_bounds__(256) void k_gemm2(
    const uint16_t* __restrict__ h1, const uint16_t* __restrict__ w2g,
    const float* __restrict__ bnsum, const float* __restrict__ bnss,
    const float* __restrict__ bng, const float* __restrict__ bnb,
    const float* __restrict__ b2, const float* __restrict__ lng,
    const float* __restrict__ lnb, float* __restrict__ out, int M, float invM)
{
    __shared__ float sbn_s[256], tbn_s[256];
    __shared__ float2 red[64][2];    // per-row (sum, sum2) per col-half
    int tid = threadIdx.x;
    {
        float mu  = bnsum[tid] * invM;
        float var = bnss[tid] * invM - mu*mu;
        float rstd = rsqrtf(fmaxf(var, 0.f) + 1e-5f);
        float sc = rstd * bng[tid];
        sbn_s[tid] = sc;
        tbn_s[tid] = bnb[tid] - mu * sc;
    }
    __syncthreads();
    int lane = tid & 63;
    int wid  = tid >> 6;
    int wm = wid >> 1, wn = wid & 1;
    int row0 = blockIdx.x * 64;
    int lr = lane & 15, lkg = lane >> 4;
    int rt16max = (M - 1) >> 4;
    f32x4 acc[2][4] = {};
    #pragma unroll
    for (int ks = 0; ks < 8; ++ks){
        int k = ks*32 + lkg*8;
        float s[8], t[8];
        *(float4*)&s[0] = *(const float4*)(sbn_s + k);
        *(float4*)&s[4] = *(const float4*)(sbn_s + k + 4);
        *(float4*)&t[0] = *(const float4*)(tbn_s + k);
        *(float4*)&t[4] = *(const float4*)(tbn_s + k + 4);
        bf16x8 a[2], b[4];
        #pragma unroll
        for (int rt = 0; rt < 2; ++rt){
            int rt16 = (row0 >> 4) + wm*2 + rt;
            if (rt16 > rt16max) rt16 = rt16max;
            bf16x8 hv = *(const bf16x8*)(h1 + (size_t)rt16*4096 + (size_t)(ks*4 + lkg)*128 + lr*8);
            union { uint32_t u[4]; bf16x8 v; } pk;
            #pragma unroll
            for (int jj = 0; jj < 4; ++jj){
                float v0 = fmaf(bfu((uint16_t)hv[2*jj]),   s[2*jj],   t[2*jj]);
                float v1 = fmaf(bfu((uint16_t)hv[2*jj+1]), s[2*jj+1], t[2*jj+1]);
                v0 = fmaxf(v0, 0.f); v1 = fmaxf(v1, 0.f);
                pk.u[jj] = pk2(v0, v1);
            }
            a[rt] = pk.v;
        }
        #pragma unroll
        for (int ct = 0; ct < 4; ++ct){
            int c16 = wn*4 + ct;
            b[ct] = *(const bf16x8*)(w2g + ((size_t)(c16*32 + ks*4 + lkg) << 7) + lr*8);
        }
        #pragma unroll
        for (int rt = 0; rt < 2; ++rt)
            #pragma unroll
            for (int ct = 0; ct < 4; ++ct)
                acc[rt][ct] = __builtin_amdgcn_mfma_f32_16x16x32_bf16(a[rt], b[ct], acc[rt][ct], 0, 0, 0);
    }
    // bias into acc; preload LN params per ct
    float lngv[4], lnbv[4];
    #pragma unroll
    for (int ct = 0; ct < 4; ++ct){
        int cl = wn*64 + ct*16 + lr;
        float bias = b2[cl];
        lngv[ct] = lng[cl];
        lnbv[ct] = lnb[cl];
        #pragma unroll
        for (int rt = 0; rt < 2; ++rt)
            #pragma unroll
            for (int rg = 0; rg < 4; ++rg)
                acc[rt][ct][rg] += bias;
    }
    // per-row partials: reduce Σv, Σv² over the 16-lane lr-group
    #pragma unroll
    for (int rt = 0; rt < 2; ++rt){
        #pragma unroll
        for (int rg = 0; rg < 4; ++rg){
            float s = 0.f, s2 = 0.f;
            #pragma unroll
            for (int ct = 0; ct < 4; ++ct){
                float v = acc[rt][ct][rg];
                s += v; s2 = fmaf(v, v, s2);
            }
            s  += __shfl_xor(s, 1);  s  += __shfl_xor(s, 2);  s  += __shfl_xor(s, 4);  s  += __shfl_xor(s, 8);
            s2 += __shfl_xor(s2, 1); s2 += __shfl_xor(s2, 2); s2 += __shfl_xor(s2, 4); s2 += __shfl_xor(s2, 8);
            if (lr == 0){
                int rl = wm*32 + rt*16 + lkg*4 + rg;
                red[rl][wn] = make_float2(s, s2);
            }
        }
    }
    __syncthreads();
    // normalize in registers, store fp32 directly
    #pragma unroll
    for (int rt = 0; rt < 2; ++rt){
        #pragma unroll
        for (int rg = 0; rg < 4; ++rg){
            int rl = wm*32 + rt*16 + lkg*4 + rg;
            int gr = row0 + rl;
            float2 p0 = red[rl][0], p1 = red[rl][1];
            float sum  = p0.x + p1.x;
            float sum2 = p0.y + p1.y;
            float mu = sum * (1.f/128.f);
            float var = sum2 * (1.f/128.f) - mu*mu;
            float rstd = rsqrtf(fmaxf(var, 0.f) + 1e-5f);
            if (gr < M){
                #pragma unroll
                for (int ct = 0; ct < 4; ++ct){
                    int cl = wn*64 + ct*16 + lr;
                    float v = (acc[rt][ct][rg] - mu) * rstd * lngv[ct] + lnbv[ct];
                    v = (v > 0.f) ? v : (fexp2(v * 1.44269504f) - 1.f);
                    out[(size_t)gr*128 + cl] = v;
                }
            }
        }
    }
}

// ---------- launcher ----------
extern "C" void kernel_launch(void* const* d_in, const int* in_sizes, int n_in,
                              void* d_out, int out_size, void* d_ws, size_t ws_size,
                              hipStream_t stream)
{
    (void)n_in; (void)out_size; (void)ws_size;
    const float* x     = (const float*)d_in[0];
    const float* eattr = (const float*)d_in[1];
    const float* ew    = (const float*)d_in[2];
    const float* eb    = (const float*)d_in[3];
    const float* t     = (const float*)d_in[4];
    const float* w1    = (const float*)d_in[5];
    const float* b1    = (const float*)d_in[6];
    const float* bng   = (const float*)d_in[7];
    const float* bnb   = (const float*)d_in[8];
    const float* w2    = (const float*)d_in[9];
    const float* b2    = (const float*)d_in[10];
    const float* lng   = (const float*)d_in[11];
    const float* lnb   = (const float*)d_in[12];
    const int*   eidx  = (const int*)d_in[13];
    int Nn = in_sizes[0] / 128;
    int E  = in_sizes[13] / 2;
    int nbkt = (Nn + 63) >> 6;          // 782

    char* ws = (char*)d_ws;
    size_t off = 0;
    auto alloc = [&](size_t bytes)->char*{
        char* p = ws + off;
        off += (bytes + 511) & ~(size_t)511;
        return p;
    };
    char* zstart   = ws;
    int*   gcnt    = (int*)  alloc((size_t)nbkt * 4);
    float* bnsum   = (float*)alloc(256 * 4);
    float* bnss    = (float*)alloc(256 * 4);
    size_t zlen    = off;
    int*   bbase   = (int*)  alloc((size_t)nbkt * 4);
    int*   offs    = (int*)  alloc((size_t)(Nn + 1) * 4);
    uint2* se      = (uint2*)alloc((size_t)E * 8);
    uint16_t* w1g  = (uint16_t*)alloc(128 * 256 * 2);
    uint16_t* w2g  = (uint16_t*)alloc(128 * 256 * 2);
    uint16_t* hbuf = (uint16_t*)alloc((size_t)Nn * 128 * 2);   // bf16 h = agg + x

    // d_out overlays:
    //   xb   = d_out[0 : Nn*128*2)              (bf16 x; live until k_agg)
    //   breg = d_out[Nn*128*2 : +nbkt*BCAP*8)   (bucket regions; live k_pre..k_bsort)
    //   h1g  = all of d_out                     (gemm1 output, fragment-group layout;
    //                                            then gemm2 final fp32)
    uint16_t* xb   = (uint16_t*)d_out;
    uint2*    breg = (uint2*)((char*)d_out + (size_t)Nn * 128 * 2);
    uint16_t* h1   = (uint16_t*)d_out;
    float*    fo   = (float*)d_out;

    int n4     = Nn * 32;
    int nb_bin = (E + 8191) / 8192;         // 98
    int nb_x   = (n4 + 1023) / 1024;        // 1563
    int nb_w   = (2*128*256 + 1023) / 1024; // 64

    hipMemsetAsync(zstart, 0, zlen, stream);
    k_pre<<<nb_bin + nb_x + nb_w, 1024, 0, stream>>>(
        eidx, eidx + E, eattr, gcnt, breg, E, nbkt, nb_bin,
        x, xb, n4, nb_x, w1, w2, w1g, w2g);
    k_bscan<<<1, 1024, 0, stream>>>(gcnt, bbase, nbkt);
    k_bsort<<<nbkt, 256, 0, stream>>>(breg, gcnt, bbase, se, offs, Nn);
    k_agg<<<(Nn + 1) / 2, 128, 0, stream>>>(xb, se, ew, eb, t, offs, hbuf, Nn);
    k_gemm1<<<(Nn + 63) / 64, 256, 0, stream>>>(hbuf, w1g, b1, bnsum, bnss, h1, Nn);
    k_gemm2<<<(Nn + 63) / 64, 256, 0, stream>>>(h1, w2g, bnsum, bnss, bng, bnb, b2, lng, lnb, fo, Nn, 1.0f/(float)Nn);
}